// Round 13
// baseline (366.662 us; speedup 1.0000x reference)
//
#include <hip/hip_runtime.h>
#include <hip/hip_bf16.h>
#include <stdint.h>

#define N_NODES 50000
#define N_EDGES 800000
#define TOT_EDGES (N_EDGES + N_NODES)
#define DIM 128
#define NEG 0.2f
#define BN_EPS 1e-5f
#define SKIPC 0.5f
#define NB 196          // buckets of 256 dst nodes
#define BCAP 6144       // per-bucket capacity (mean 4082, +31 sigma)

typedef __attribute__((ext_vector_type(8))) short short8;
typedef __attribute__((ext_vector_type(4))) float f32x4;

// ---------- helpers ----------
__device__ inline float bf2f(__hip_bfloat16 v) { return __bfloat162float(v); }
__device__ inline float u16f(unsigned short u) { return __uint_as_float(((unsigned int)u) << 16); }
__device__ inline unsigned short f2bu(float f) {
    __hip_bfloat16 b = __float2bfloat16(f);
    return *(unsigned short*)&b;
}
__device__ inline void fma8(float* acc, float ex, uint4 u) {
    acc[0] += ex * u16f((unsigned short)(u.x & 0xFFFFu));
    acc[1] += ex * u16f((unsigned short)(u.x >> 16));
    acc[2] += ex * u16f((unsigned short)(u.y & 0xFFFFu));
    acc[3] += ex * u16f((unsigned short)(u.y >> 16));
    acc[4] += ex * u16f((unsigned short)(u.z & 0xFFFFu));
    acc[5] += ex * u16f((unsigned short)(u.z >> 16));
    acc[6] += ex * u16f((unsigned short)(u.w & 0xFFFFu));
    acc[7] += ex * u16f((unsigned short)(u.w >> 16));
}
__device__ inline unsigned int pk2(float a, float b) {
    return (unsigned int)f2bu(a) | ((unsigned int)f2bu(b) << 16);
}

// ---------- fallback (ws too small) ----------
__global__ void zero_out_k(unsigned short* out, int n) {
    int g = blockIdx.x * 256 + threadIdx.x;
    if (g < n) out[g] = 0;
}

// ---------- CSR build, bucketed (self-detects int64/int32 edges) ----------
__global__ __launch_bounds__(256) void binA_k(const int* __restrict__ ei,
                                              int* __restrict__ bcnt,
                                              unsigned int* __restrict__ pairs) {
    __shared__ int cnt[NB], base[NB], cur[NB];
    __shared__ int sf;
    int t = threadIdx.x;
    if (t == 0) sf = 0;
    for (int i = t; i < NB; i += 256) cnt[i] = 0;
    __syncthreads();
    if (t < 16 && ei[2 * t + 1] != 0) atomicOr(&sf, 1);
    __syncthreads();
    int f = (sf == 0);   // 1 => int64
    int b0 = blockIdx.x * 4096;
    unsigned int pk[16];
    int bk[16];
    #pragma unroll
    for (int j = 0; j < 16; ++j) {
        int g = b0 + j * 256 + t;
        bk[j] = -1;
        if (g < N_EDGES) {
            int s, d;
            if (f) { s = ei[2 * g]; d = ei[2 * (N_EDGES + g)]; }
            else   { s = ei[g];     d = ei[N_EDGES + g]; }
            if ((unsigned)d < N_NODES && (unsigned)s < N_NODES) {
                bk[j] = d >> 8;
                pk[j] = (unsigned int)s | ((unsigned int)(d & 255) << 16);
                atomicAdd(&cnt[bk[j]], 1);
            }
        }
    }
    __syncthreads();
    if (t < NB) {
        int c = cnt[t];
        base[t] = c ? atomicAdd(&bcnt[t], c) : 0;
        cur[t] = 0;
    }
    __syncthreads();
    #pragma unroll
    for (int j = 0; j < 16; ++j) {
        if (bk[j] >= 0) {
            int off = base[bk[j]] + atomicAdd(&cur[bk[j]], 1);
            if (off < BCAP) pairs[(size_t)bk[j] * BCAP + off] = pk[j];
        }
    }
}

__global__ __launch_bounds__(256) void bucketscan_k(const int* __restrict__ bcnt,
                                                    int* __restrict__ bbase,
                                                    int* __restrict__ row_ptr) {
    __shared__ int sm[256];
    int t = threadIdx.x;
    int v = 0;
    if (t < NB) {
        int nn = min(256, N_NODES - t * 256);
        v = min(bcnt[t], BCAP) + nn;
    }
    sm[t] = v;
    __syncthreads();
    for (int off = 1; off < 256; off <<= 1) {
        int x = (t >= off) ? sm[t - off] : 0;
        __syncthreads();
        sm[t] += x;
        __syncthreads();
    }
    if (t < NB) bbase[t] = sm[t] - v;
    if (t == 255) row_ptr[N_NODES] = sm[255];
}

__global__ __launch_bounds__(256) void binB_k(const int* __restrict__ bcnt,
                                              const int* __restrict__ bbase,
                                              const unsigned int* __restrict__ pairs,
                                              int* __restrict__ row_ptr,
                                              int* __restrict__ ssrc) {
    __shared__ int cntL[256], scanL[256], curL[256];
    int b = blockIdx.x, t = threadIdx.x;
    int n0 = b * 256;
    int nn = min(256, N_NODES - n0);
    int cnt_b = min(bcnt[b], BCAP);
    const unsigned int* P = pairs + (size_t)b * BCAP;
    cntL[t] = (t < nn) ? 1 : 0;
    __syncthreads();
    for (int i = t; i < cnt_b; i += 256)
        atomicAdd(&cntL[P[i] >> 16], 1);
    __syncthreads();
    int v = cntL[t];
    scanL[t] = v;
    __syncthreads();
    for (int off = 1; off < 256; off <<= 1) {
        int x = (t >= off) ? scanL[t - off] : 0;
        __syncthreads();
        scanL[t] += x;
        __syncthreads();
    }
    int excl = scanL[t] - v;
    int gbase = bbase[b];
    if (t < nn) row_ptr[n0 + t] = gbase + excl;
    curL[t] = excl;
    __syncthreads();
    if (t < nn) {
        int pos = atomicAdd(&curL[t], 1);
        ssrc[gbase + pos] = n0 + t;
    }
    for (int i = t; i < cnt_b; i += 256) {
        unsigned int p = P[i];
        int pos = atomicAdd(&curL[p >> 16], 1);
        ssrc[gbase + pos] = (int)(p & 0xFFFFu);
    }
}

// ---------- merged W-convert + small-param convert + float-dtype detect ----------
// Each block independently votes on W0's dtype (bf16 vs f32) from its first
// 256 words; block 0 publishes fflag for downstream kernels.
struct PrepJobs { const void* src[13]; float* dst[13]; int n[13]; };
__global__ __launch_bounds__(256) void wcvt_k(const void* __restrict__ W0,
                                              const void* __restrict__ W1,
                                              const void* __restrict__ W2,
                                              unsigned short* __restrict__ Wb0,
                                              unsigned short* __restrict__ Wb1,
                                              unsigned short* __restrict__ Wb2,
                                              PrepJobs jobs,
                                              int* __restrict__ fflag) {
    __shared__ int cs;
    int t = threadIdx.x;
    if (t == 0) cs = 0;
    __syncthreads();
    unsigned int wv = ((const unsigned int*)W0)[t];
    float v0 = u16f((unsigned short)(wv & 0xFFFFu));
    float av = fabsf(v0);
    if (av < 2.0f && (av > 1e-20f || v0 == 0.0f)) atomicAdd(&cs, 1);
    __syncthreads();
    int f = (cs >= 128);   // 1 => bf16
    if (blockIdx.x == 0 && t == 0) fflag[0] = f;

    int b = blockIdx.x;
    if (b < 148) {
        int g = b * 256 + t;
        const void* W; unsigned short* Wb; int idx;
        if (g < 16384)        { W = W0; Wb = Wb0; idx = g; }
        else if (g < 32768)   { W = W1; Wb = Wb1; idx = g - 16384; }
        else if (g < 37888)   { W = W2; Wb = Wb2; idx = g - 32768; }
        else return;
        if (f) Wb[idx] = ((const unsigned short*)W)[idx];
        else   Wb[idx] = f2bu(((const float*)W)[idx]);
    } else {
        int j = b - 148;
        int n = jobs.n[j];
        const void* s = jobs.src[j];
        float* d = jobs.dst[j];
        for (int i = t; i < n; i += 256)
            d[i] = f ? bf2f(((const __hip_bfloat16*)s)[i]) : ((const float*)s)[i];
    }
}

// ---------- extended-weight build: AL columns ----------
__global__ __launch_bounds__(256) void wext_k(unsigned short* __restrict__ Wb0,
                                              unsigned short* __restrict__ Wb1,
                                              unsigned short* __restrict__ Wb2,
                                              const float* __restrict__ pAs0, const float* __restrict__ pAd0,
                                              const float* __restrict__ pAs1, const float* __restrict__ pAd1,
                                              const float* __restrict__ pAs2, const float* __restrict__ pAd2) {
    int g = blockIdx.x * 256 + threadIdx.x;
    if (g < 2048) {
        int layer = g >> 10;
        int gi = g & 1023;
        int rowq = gi >> 7;
        int k = gi & 127;
        int hh = rowq & 3, dir = rowq >> 2;
        unsigned short* Wb = layer ? Wb1 : Wb0;
        const float* p = layer ? (dir ? pAd1 : pAs1) : (dir ? pAd0 : pAs0);
        float v = 0.f;
        #pragma unroll
        for (int c = 0; c < 32; ++c)
            v += p[hh * 32 + c] * u16f(Wb[(size_t)(hh * 32 + c) * 128 + k]);
        Wb[(size_t)(128 + dir * 4 + hh) * 128 + k] = f2bu(v);
    } else if (g < 2304) {
        int gi = g - 2048;
        int dir = gi >> 7;
        int k = gi & 127;
        const float* p = dir ? pAd2 : pAs2;
        float v = 0.f;
        #pragma unroll
        for (int c = 0; c < 40; ++c)
            v += p[c] * u16f(Wb2[(size_t)c * 128 + k]);
        Wb2[(size_t)(40 + dir) * 128 + k] = f2bu(v);
    }
}

// ---------- BN coefficients: (sum,sumsq,g,be) -> (scale,shift) ----------
__global__ void bn_coef_k(const float* __restrict__ sums,
                          const float* __restrict__ g, const float* __restrict__ be,
                          float* __restrict__ coef) {
    int t = threadIdx.x;
    if (t >= 128) return;
    const float invN = 1.f / (float)N_NODES;
    float mean = sums[t] * invN;
    float var = fmaxf(sums[128 + t] * invN - mean * mean, 0.f);
    float sc = g[t] * rsqrtf(var + BN_EPS);
    coef[t] = sc;
    coef[128 + t] = be[t] - mean * sc;
}

// ---------- MFMA GEMM core (A-fragment supplied by functor-less variants) ----
// All register indexing static (round-9 trap guard).
template<int MT, int MV, int ALBASE, int NH>
__device__ inline void mfma_core(short8 (&aF)[4],
                                 const unsigned short* __restrict__ Wb,
                                 unsigned short* __restrict__ Y,
                                 float* __restrict__ als, float* __restrict__ ald,
                                 int r0, int lane, int n) {
    const int MROWS = ALBASE + 2 * NH;
    int m = lane & 15, quad = lane >> 4;
    f32x4 acc[MT];
    #pragma unroll
    for (int t = 0; t < MT; ++t) acc[t] = (f32x4){0.f, 0.f, 0.f, 0.f};
    #pragma unroll
    for (int kc = 0; kc < 4; ++kc) {
        int k0 = kc * 32 + quad * 8;
        #pragma unroll
        for (int t = 0; t < MT; ++t) {
            int col = t * 16 + m;
            short8 b;
            if (col < MROWS) b = *(const short8*)(Wb + (size_t)col * 128 + k0);
            else             b = (short8){0,0,0,0,0,0,0,0};
            acc[t] = __builtin_amdgcn_mfma_f32_16x16x32_bf16(aF[kc], b, acc[t], 0, 0, 0);
        }
    }
    #pragma unroll
    for (int t = 0; t < MT; ++t) {
        int col = t * 16 + m;
        #pragma unroll
        for (int r = 0; r < 4; ++r) {
            int row = r0 + quad * 4 + r;
            if (row >= n) continue;
            if (col < MV) {
                Y[(size_t)row * MV + col] = f2bu(acc[t][r]);
            } else if (col < ALBASE + NH) {
                als[row * NH + (col - ALBASE)] = acc[t][r];
            } else if (col < ALBASE + 2 * NH) {
                ald[row * NH + (col - ALBASE - NH)] = acc[t][r];
            }
        }
    }
}

// layer 0: A = x (bf16 or f32 per fflag)
__global__ __launch_bounds__(256) void mfma_x_k(const void* __restrict__ X,
                                                const unsigned short* __restrict__ Wb,
                                                unsigned short* __restrict__ Y,
                                                float* __restrict__ als, float* __restrict__ ald,
                                                int n, const int* __restrict__ fflag) {
    int wave = (blockIdx.x * blockDim.x + threadIdx.x) >> 6;
    int r0 = wave * 16;
    if (r0 >= n) return;
    int lane = threadIdx.x & 63;
    int arow = min(r0 + (lane & 15), n - 1);
    int quad = lane >> 4;
    short8 aF[4];
    if (fflag[0]) {
        #pragma unroll
        for (int kc = 0; kc < 4; ++kc)
            aF[kc] = *(const short8*)((const unsigned short*)X + (size_t)arow * 128 + kc * 32 + quad * 8);
    } else {
        #pragma unroll
        for (int kc = 0; kc < 4; ++kc) {
            const float* xp = (const float*)X + (size_t)arow * 128 + kc * 32 + quad * 8;
            float4 x0 = *(const float4*)xp;
            float4 x1 = *(const float4*)(xp + 4);
            aF[kc][0] = (short)f2bu(x0.x); aF[kc][1] = (short)f2bu(x0.y);
            aF[kc][2] = (short)f2bu(x0.z); aF[kc][3] = (short)f2bu(x0.w);
            aF[kc][4] = (short)f2bu(x1.x); aF[kc][5] = (short)f2bu(x1.y);
            aF[kc][6] = (short)f2bu(x1.z); aF[kc][7] = (short)f2bu(x1.w);
        }
    }
    mfma_core<9, 128, 128, 4>(aF, Wb, Y, als, ald, r0, lane, n);
}

// layer 1: A = relu(bn0(hAgg0))  — fused affine on load
__global__ __launch_bounds__(256) void mfma_bn1_k(const unsigned short* __restrict__ hA0,
                                                  const float* __restrict__ coef0,
                                                  const unsigned short* __restrict__ Wb,
                                                  unsigned short* __restrict__ Y,
                                                  float* __restrict__ als, float* __restrict__ ald,
                                                  int n) {
    int wave = (blockIdx.x * blockDim.x + threadIdx.x) >> 6;
    int r0 = wave * 16;
    if (r0 >= n) return;
    int lane = threadIdx.x & 63;
    int arow = min(r0 + (lane & 15), n - 1);
    int quad = lane >> 4;
    short8 aF[4];
    #pragma unroll
    for (int kc = 0; kc < 4; ++kc) {
        int k0 = kc * 32 + quad * 8;
        uint4 ux = *(const uint4*)(hA0 + (size_t)arow * 128 + k0);
        float4 scA = *(const float4*)(coef0 + k0);
        float4 scB = *(const float4*)(coef0 + k0 + 4);
        float4 shA = *(const float4*)(coef0 + 128 + k0);
        float4 shB = *(const float4*)(coef0 + 128 + k0 + 4);
        float v[8];
        v[0] = u16f((unsigned short)(ux.x & 0xFFFFu)); v[1] = u16f((unsigned short)(ux.x >> 16));
        v[2] = u16f((unsigned short)(ux.y & 0xFFFFu)); v[3] = u16f((unsigned short)(ux.y >> 16));
        v[4] = u16f((unsigned short)(ux.z & 0xFFFFu)); v[5] = u16f((unsigned short)(ux.z >> 16));
        v[6] = u16f((unsigned short)(ux.w & 0xFFFFu)); v[7] = u16f((unsigned short)(ux.w >> 16));
        aF[kc][0] = (short)f2bu(fmaxf(scA.x * v[0] + shA.x, 0.f));
        aF[kc][1] = (short)f2bu(fmaxf(scA.y * v[1] + shA.y, 0.f));
        aF[kc][2] = (short)f2bu(fmaxf(scA.z * v[2] + shA.z, 0.f));
        aF[kc][3] = (short)f2bu(fmaxf(scA.w * v[3] + shA.w, 0.f));
        aF[kc][4] = (short)f2bu(fmaxf(scB.x * v[4] + shB.x, 0.f));
        aF[kc][5] = (short)f2bu(fmaxf(scB.y * v[5] + shB.y, 0.f));
        aF[kc][6] = (short)f2bu(fmaxf(scB.z * v[6] + shB.z, 0.f));
        aF[kc][7] = (short)f2bu(fmaxf(scB.w * v[7] + shB.w, 0.f));
    }
    mfma_core<9, 128, 128, 4>(aF, Wb, Y, als, ald, r0, lane, n);
}

// layer 2: A = relu(bn1(hAgg1) + 0.5*relu(bn0(hAgg0)))
__global__ __launch_bounds__(256) void mfma_bn2_k(const unsigned short* __restrict__ hA1,
                                                  const unsigned short* __restrict__ hA0,
                                                  const float* __restrict__ coef1,
                                                  const float* __restrict__ coef0,
                                                  const unsigned short* __restrict__ Wb,
                                                  unsigned short* __restrict__ Y,
                                                  float* __restrict__ als, float* __restrict__ ald,
                                                  int n) {
    int wave = (blockIdx.x * blockDim.x + threadIdx.x) >> 6;
    int r0 = wave * 16;
    if (r0 >= n) return;
    int lane = threadIdx.x & 63;
    int arow = min(r0 + (lane & 15), n - 1);
    int quad = lane >> 4;
    short8 aF[4];
    #pragma unroll
    for (int kc = 0; kc < 4; ++kc) {
        int k0 = kc * 32 + quad * 8;
        uint4 u1 = *(const uint4*)(hA1 + (size_t)arow * 128 + k0);
        uint4 u0 = *(const uint4*)(hA0 + (size_t)arow * 128 + k0);
        float v1[8], v0[8];
        v1[0] = u16f((unsigned short)(u1.x & 0xFFFFu)); v1[1] = u16f((unsigned short)(u1.x >> 16));
        v1[2] = u16f((unsigned short)(u1.y & 0xFFFFu)); v1[3] = u16f((unsigned short)(u1.y >> 16));
        v1[4] = u16f((unsigned short)(u1.z & 0xFFFFu)); v1[5] = u16f((unsigned short)(u1.z >> 16));
        v1[6] = u16f((unsigned short)(u1.w & 0xFFFFu)); v1[7] = u16f((unsigned short)(u1.w >> 16));
        v0[0] = u16f((unsigned short)(u0.x & 0xFFFFu)); v0[1] = u16f((unsigned short)(u0.x >> 16));
        v0[2] = u16f((unsigned short)(u0.y & 0xFFFFu)); v0[3] = u16f((unsigned short)(u0.y >> 16));
        v0[4] = u16f((unsigned short)(u0.z & 0xFFFFu)); v0[5] = u16f((unsigned short)(u0.z >> 16));
        v0[6] = u16f((unsigned short)(u0.w & 0xFFFFu)); v0[7] = u16f((unsigned short)(u0.w >> 16));
        #pragma unroll
        for (int j = 0; j < 8; ++j) {
            int c = k0 + j;
            float s0 = fmaxf(coef0[c] * v0[j] + coef0[128 + c], 0.f);
            float v = coef1[c] * v1[j] + coef1[128 + c] + SKIPC * s0;
            aF[kc][j] = (short)f2bu(fmaxf(v, 0.f));
        }
    }
    mfma_core<3, 40, 40, 1>(aF, Wb, Y, als, ald, r0, lane, n);
}

// ---------- GAT aggregation: 2-deep pipelined gather, bf16 output ----------
template<int H, int C, int LPG, int CPL, bool FINAL>
__global__ __launch_bounds__(256) void agg4_k(const unsigned short* __restrict__ hbuf,
                                              const float* __restrict__ als,
                                              const float* __restrict__ ald,
                                              const float* __restrict__ bias,
                                              const int* __restrict__ row_ptr,
                                              const int* __restrict__ ssrc,
                                              void* __restrict__ out,
                                              const int* __restrict__ fflag, int n) {
    const int HC = H * C;
    const int G = 64 / LPG;
    const int NV = CPL / 8;
    int gw = (blockIdx.x * blockDim.x + threadIdx.x) >> 6;
    if (gw >= n) return;
    int lane = threadIdx.x & 63;
    int grp = lane / LPG;
    int sl  = lane % LPG;
    int c0 = sl * CPL;
    bool act = c0 < HC;
    int hl = act ? (c0 / C) : 0;
    int d = gw;
    int beg = row_ptr[d], end = row_ptr[d + 1];
    float adh = ald[d * H + hl];

    float denom = 0.f;
    float acc[CPL];
    #pragma unroll
    for (int j = 0; j < CPL; ++j) acc[j] = 0.f;

    int i0 = beg + grp;
    bool h0 = i0 < end;
    bool h1 = (i0 + G) < end;
    float al0 = 0.f, al1 = 0.f;
    uint4 u0[NV], u1[NV];
    if (h0) {
        int s = ssrc[i0];
        al0 = als[s * H + hl];
        if (act) {
            const uint4* hp = (const uint4*)(hbuf + (size_t)s * HC + c0);
            #pragma unroll
            for (int v = 0; v < NV; ++v) u0[v] = hp[v];
        }
    }
    if (h1) {
        int s = ssrc[i0 + G];
        al1 = als[s * H + hl];
        if (act) {
            const uint4* hp = (const uint4*)(hbuf + (size_t)s * HC + c0);
            #pragma unroll
            for (int v = 0; v < NV; ++v) u1[v] = hp[v];
        }
    }
    int inext = i0 + 2 * G;

    while (h0) {
        bool h2 = inext < end;
        float al2 = 0.f;
        uint4 u2[NV];
        if (h2) {
            int s = ssrc[inext];
            al2 = als[s * H + hl];
            if (act) {
                const uint4* hp = (const uint4*)(hbuf + (size_t)s * HC + c0);
                #pragma unroll
                for (int v = 0; v < NV; ++v) u2[v] = hp[v];
            }
        }
        float t = al0 + adh;
        t = t > 0.f ? t : NEG * t;
        float ex = __expf(t);
        denom += ex;
        if (act) {
            #pragma unroll
            for (int v = 0; v < NV; ++v) fma8(acc + v * 8, ex, u0[v]);
        }
        h0 = h1; al0 = al1;
        #pragma unroll
        for (int v = 0; v < NV; ++v) u0[v] = u1[v];
        h1 = h2; al1 = al2;
        #pragma unroll
        for (int v = 0; v < NV; ++v) u1[v] = u2[v];
        inext += G;
    }

    #pragma unroll
    for (int off = LPG; off < 64; off <<= 1) {
        denom += __shfl_xor(denom, off, 64);
        #pragma unroll
        for (int j = 0; j < CPL; ++j) acc[j] += __shfl_xor(acc[j], off, 64);
    }

    if (grp == 0 && act) {
        float inv = 1.f / denom;
        float vals[CPL];
        #pragma unroll
        for (int j = 0; j < CPL; ++j) vals[j] = acc[j] * inv + bias[c0 + j];
        if (FINAL && !fflag[0]) {
            float* of = (float*)out + (size_t)d * HC + c0;
            #pragma unroll
            for (int j = 0; j < CPL; ++j) of[j] = vals[j];
        } else {
            unsigned short* ob = (unsigned short*)out + (size_t)d * HC + c0;
            #pragma unroll
            for (int v = 0; v < NV; ++v) {
                uint4 pk;
                pk.x = pk2(vals[v * 8 + 0], vals[v * 8 + 1]);
                pk.y = pk2(vals[v * 8 + 2], vals[v * 8 + 3]);
                pk.z = pk2(vals[v * 8 + 4], vals[v * 8 + 5]);
                pk.w = pk2(vals[v * 8 + 6], vals[v * 8 + 7]);
                *(uint4*)(ob + v * 8) = pk;
            }
        }
    }
}

// ---------- BatchNorm stats (bf16 input) ----------
__global__ __launch_bounds__(256) void bn_stats_k(const unsigned short* __restrict__ x,
                                                  float* __restrict__ sum,
                                                  float* __restrict__ sumsq, int n) {
    __shared__ float ss[256], sq[256];
    int t = threadIdx.x;
    int c = t & 127, half = t >> 7;
    float s = 0.f, s2 = 0.f;
    for (int r = blockIdx.x * 2 + half; r < n; r += gridDim.x * 2) {
        float v = u16f(x[(size_t)r * 128 + c]);
        s += v; s2 += v * v;
    }
    ss[t] = s; sq[t] = s2;
    __syncthreads();
    if (t < 128) {
        s = ss[t] + ss[t + 128];
        s2 = sq[t] + sq[t + 128];
        atomicAdd(&sum[c], s);
        atomicAdd(&sumsq[c], s2);
    }
}

// ---------- launch ----------
extern "C" void kernel_launch(void* const* d_in, const int* in_sizes, int n_in,
                              void* d_out, int out_size, void* d_ws, size_t ws_size,
                              hipStream_t stream) {
    const void* x   = d_in[0];
    const void* W0  = d_in[1];
    const void* as0 = d_in[2];
    const void* ad0 = d_in[3];
    const void* b0  = d_in[4];
    const void* g0  = d_in[5];
    const void* be0 = d_in[6];
    const void* W1  = d_in[7];
    const void* as1 = d_in[8];
    const void* ad1 = d_in[9];
    const void* b1  = d_in[10];
    const void* g1  = d_in[11];
    const void* be1 = d_in[12];
    const void* W2  = d_in[13];
    const void* as2 = d_in[14];
    const void* ad2 = d_in[15];
    const void* b2  = d_in[16];
    const int* ei = (const int*)d_in[17];

    char* w = (char*)d_ws;
    size_t off = 0;
    auto alloc = [&](size_t bytes) -> void* {
        void* p = w + off;
        off = (off + bytes + 255) & ~(size_t)255;
        return p;
    };
    unsigned short* hAgg0 = (unsigned short*)alloc((size_t)N_NODES * 128 * 2);
    unsigned short* hAgg1 = (unsigned short*)alloc((size_t)N_NODES * 128 * 2);
    unsigned short* hbf   = (unsigned short*)alloc((size_t)N_NODES * 128 * 2);
    float* als = (float*)alloc((size_t)N_NODES * 4 * 4);
    float* ald = (float*)alloc((size_t)N_NODES * 4 * 4);
    unsigned short* Wb0 = (unsigned short*)alloc((size_t)136 * 128 * 2);
    unsigned short* Wb1 = (unsigned short*)alloc((size_t)136 * 128 * 2);
    unsigned short* Wb2 = (unsigned short*)alloc((size_t)42 * 128 * 2);
    float* prm = (float*)alloc(2048 * 4);
    float* coef0 = (float*)alloc(256 * 4);
    float* coef1 = (float*)alloc(256 * 4);
    // contiguous zero-region: bcnt[NB] | bn0[256] | bn1[256]
    int* zreg = (int*)alloc((size_t)(NB + 512) * 4);
    int* bcnt = zreg;
    float* bn0 = (float*)(zreg + NB);
    float* bn1 = bn0 + 256;
    int* row_ptr = (int*)alloc((size_t)(N_NODES + 1) * 4);
    int* ssrc    = (int*)alloc((size_t)TOT_EDGES * 4);
    unsigned int* pairs = (unsigned int*)alloc((size_t)NB * BCAP * 4);
    int* bbase   = (int*)alloc((size_t)NB * 4);
    int* fflag   = (int*)alloc(256);

    float* pAs0 = prm + 0,   * pAd0 = prm + 128,  * pB0 = prm + 256;
    float* pG0  = prm + 384, * pBe0 = prm + 512;
    float* pAs1 = prm + 640, * pAd1 = prm + 768,  * pB1 = prm + 896;
    float* pG1  = prm + 1024,* pBe1 = prm + 1152;
    float* pAs2 = prm + 1280,* pAd2 = prm + 1320, * pB2 = prm + 1360;

    if (off > ws_size) {
        zero_out_k<<<(out_size + 255) / 256, 256, 0, stream>>>((unsigned short*)d_out, out_size);
        return;
    }

    const int MB = (((N_NODES + 15) / 16) + 3) / 4;
    const int AB = (N_NODES * 64 + 255) / 256;

    // --- bucketed CSR build ---
    hipMemsetAsync(zreg, 0, (size_t)(NB + 512) * 4, stream);
    binA_k<<<(N_EDGES + 4095) / 4096, 256, 0, stream>>>(ei, bcnt, pairs);
    bucketscan_k<<<1, 256, 0, stream>>>(bcnt, bbase, row_ptr);
    binB_k<<<NB, 256, 0, stream>>>(bcnt, bbase, pairs, row_ptr, ssrc);

    // --- param conversion (self-detecting) + extended weights ---
    PrepJobs jobs;
    const void* srcs[13] = { as0, ad0, b0, g0, be0, as1, ad1, b1, g1, be1, as2, ad2, b2 };
    float* dsts[13] = { pAs0, pAd0, pB0, pG0, pBe0, pAs1, pAd1, pB1, pG1, pBe1, pAs2, pAd2, pB2 };
    int ns[13] = { 128,128,128,128,128, 128,128,128,128,128, 40,40,40 };
    for (int i = 0; i < 13; ++i) { jobs.src[i] = srcs[i]; jobs.dst[i] = dsts[i]; jobs.n[i] = ns[i]; }
    wcvt_k<<<161, 256, 0, stream>>>(W0, W1, W2, Wb0, Wb1, Wb2, jobs, fflag);
    wext_k<<<9, 256, 0, stream>>>(Wb0, Wb1, Wb2, pAs0, pAd0, pAs1, pAd1, pAs2, pAd2);

    // --- layer 0 ---
    mfma_x_k<<<MB, 256, 0, stream>>>(x, Wb0, hbf, als, ald, N_NODES, fflag);
    agg4_k<4, 32, 8, 16, false><<<AB, 256, 0, stream>>>(hbf, als, ald, pB0, row_ptr, ssrc, hAgg0, fflag, N_NODES);
    bn_stats_k<<<256, 256, 0, stream>>>(hAgg0, bn0, bn0 + 128, N_NODES);
    bn_coef_k<<<1, 128, 0, stream>>>(bn0, pG0, pBe0, coef0);

    // --- layer 1 (BN0+ReLU fused into A-load) ---
    mfma_bn1_k<<<MB, 256, 0, stream>>>(hAgg0, coef0, Wb1, hbf, als, ald, N_NODES);
    agg4_k<4, 32, 8, 16, false><<<AB, 256, 0, stream>>>(hbf, als, ald, pB1, row_ptr, ssrc, hAgg1, fflag, N_NODES);
    bn_stats_k<<<256, 256, 0, stream>>>(hAgg1, bn1, bn1 + 128, N_NODES);
    bn_coef_k<<<1, 128, 0, stream>>>(bn1, pG1, pBe1, coef1);

    // --- layer 2 (BN1+skip+ReLU fused into A-load) ---
    mfma_bn2_k<<<MB, 256, 0, stream>>>(hAgg1, hAgg0, coef1, coef0, Wb2, hbf, als, ald, N_NODES);
    agg4_k<1, 40, 8, 8, true><<<AB, 256, 0, stream>>>(hbf, als, ald, pB2, row_ptr, ssrc, d_out, fflag, N_NODES);
}